// Round 2
// baseline (2920.839 us; speedup 1.0000x reference)
//
#include <hip/hip_runtime.h>
#include <hip/hip_bf16.h>

// ---- problem constants (from setup_inputs; scalars fixed: 4, 56, 56) ----
#define B_     16
#define NBAND  4
#define HP     56
#define WP     56
#define C_     96
#define NHEADS 3
#define HD     32
#define WSZ    7
#define SHIFT_ 3
#define NT     196                 // NBAND*WSZ*WSZ tokens per window
#define BW     (B_ * 8 * 8)        // 1024 windows
#define HID    384
#define L_     (NBAND * HP * WP)   // 12544
#define NTOK   (B_ * L_)           // 200704

typedef unsigned short u16;
typedef __attribute__((ext_vector_type(8))) unsigned short ushort8;

__device__ __forceinline__ float bf2f(u16 u) {
    union { float f; unsigned int i; } x;
    x.i = ((unsigned int)u) << 16;
    return x.f;
}
__device__ __forceinline__ u16 f2bf(float f) {
    union { float f; unsigned int i; } x;
    x.f = f;
    unsigned int r = x.i + 0x7fffu + ((x.i >> 16) & 1u);  // RNE
    return (u16)(r >> 16);
}

// =====================================================================
// Kernel 1: windowed attention (QKV + softmax + PV + proj), scatter to out
// one block per window; x-tile + K,V staged in LDS as bf16; fp32 accum
// =====================================================================
#define KV_LD 200   // padded row stride for K|V rows (u16 elements)
#define XS_LD 98    // padded row stride for x tile (odd word count -> fewer conflicts)

__global__ __launch_bounds__(640) void attn_win_kernel(
    const float* __restrict__ x,
    const float* __restrict__ qkv_w,   // (96, 288)
    const float* __restrict__ qkv_b,   // (288)
    const float* __restrict__ proj_w,  // (96, 96)
    const float* __restrict__ proj_b,  // (96)
    float* __restrict__ out)
{
    __shared__ __align__(16) u16 kv[NT * KV_LD];   // 78,400 B  (K cols 0..95 | V cols 96..191)
    __shared__ u16 xs[NT * XS_LD];                 // 38,416 B  (window's x rows, bf16)

    const int wi  = blockIdx.x;           // window id
    const int b   = wi >> 6;
    const int ih  = (wi >> 3) & 7;
    const int iw  = wi & 7;
    const int tid = threadIdx.x;

    // token t=(n,r,col) -> flat row in (B*L); roll(-3) gather == roll(+3) scatter
    auto rowOf = [&](int t) -> int {
        int n  = t / 49;
        int rc = t - n * 49;
        int r  = rc / 7, cl = rc - r * 7;
        int hh = ih * 7 + r  + SHIFT_; if (hh >= HP) hh -= HP;
        int ww = iw * 7 + cl + SHIFT_; if (ww >= WP) ww -= WP;
        return ((b * NBAND + n) * HP + hh) * WP + ww;
    };

    // ---- Phase 0: stage x window tile into LDS (bf16) ----
    for (int idx = tid; idx < NT * C_; idx += 640) {
        int t = idx / C_, c = idx - t * C_;
        xs[t * XS_LD + c] = f2bf(x[(size_t)rowOf(t) * C_ + c]);
    }
    __syncthreads();

    // ---- Phase A: K,V -> LDS (qkv columns 96..287) ----
    for (int idx = tid; idx < NT * 192; idx += 640) {
        int t  = idx / 192;
        int c  = idx - t * 192;
        int qc = 96 + c;
        float acc = qkv_b[qc];
        #pragma unroll 4
        for (int k = 0; k < C_; ++k)
            acc += bf2f(xs[t * XS_LD + k]) * qkv_w[k * 288 + qc];
        kv[t * KV_LD + c] = f2bf(acc);
    }
    __syncthreads();

    // ---- Phase B: attention, one (t, head) pair per thread (588 active) ----
    float o[HD];
    int pt = -1, ph = 0;
    if (tid < NT * NHEADS) {
        pt = tid % NT;
        ph = tid / NT;
        const int qb = ph * HD;              // q column base

        float q[HD];
        #pragma unroll
        for (int d = 0; d < HD; ++d) q[d] = qkv_b[qb + d];
        for (int k = 0; k < C_; ++k) {
            float xk = bf2f(xs[pt * XS_LD + k]);
            const float* wr = qkv_w + k * 288 + qb;
            #pragma unroll
            for (int d = 0; d < HD; ++d) q[d] += xk * wr[d];
        }
        const float scale = 0.17677669529663687f;   // 32^-0.5, folded into q
        #pragma unroll
        for (int d = 0; d < HD; ++d) q[d] *= scale;

        // pass 1: running max
        float m = -1e30f;
        for (int kk = 0; kk < NT; ++kk) {
            const ushort8* kr = (const ushort8*)&kv[kk * KV_LD + qb];
            float s = 0.f;
            #pragma unroll
            for (int c8 = 0; c8 < 4; ++c8) {
                ushort8 kx = kr[c8];
                #pragma unroll
                for (int j = 0; j < 8; ++j) s += q[c8 * 8 + j] * bf2f(kx[j]);
            }
            m = fmaxf(m, s);
        }
        // pass 2: exp-sum + PV accumulate
        float sum = 0.f;
        #pragma unroll
        for (int d = 0; d < HD; ++d) o[d] = 0.f;
        for (int kk = 0; kk < NT; ++kk) {
            const ushort8* kr = (const ushort8*)&kv[kk * KV_LD + qb];
            const ushort8* vr = (const ushort8*)&kv[kk * KV_LD + 96 + qb];
            float s = 0.f;
            #pragma unroll
            for (int c8 = 0; c8 < 4; ++c8) {
                ushort8 kx = kr[c8];
                #pragma unroll
                for (int j = 0; j < 8; ++j) s += q[c8 * 8 + j] * bf2f(kx[j]);
            }
            float p = __expf(s - m);
            sum += p;
            #pragma unroll
            for (int c8 = 0; c8 < 4; ++c8) {
                ushort8 vx = vr[c8];
                #pragma unroll
                for (int j = 0; j < 8; ++j) o[c8 * 8 + j] += p * bf2f(vx[j]);
            }
        }
        float inv = 1.f / sum;
        #pragma unroll
        for (int d = 0; d < HD; ++d) o[d] *= inv;
    }
    __syncthreads();                 // all K/V reads complete
    if (pt >= 0) {
        #pragma unroll
        for (int d = 0; d < HD; ++d) kv[pt * KV_LD + ph * HD + d] = f2bf(o[d]);
    }
    __syncthreads();

    // ---- Phase C: proj + bias, scatter to out (window-reverse + roll(+3)) ----
    for (int idx = tid; idx < NT * C_; idx += 640) {
        int t = idx / 96;
        int c = idx - t * 96;
        float acc = proj_b[c];
        #pragma unroll 4
        for (int k = 0; k < C_; ++k)
            acc += bf2f(kv[t * KV_LD + k]) * proj_w[k * 96 + c];
        out[(size_t)rowOf(t) * C_ + c] = acc;
    }
}

// =====================================================================
// Kernel 2: row-wise  x2 += LN1(x2);  x2 += fc2(gelu(fc1(LN2(x2))))
// in-place on d_out; 16 tokens per 256-thread block
// =====================================================================
#define TOK 16

__global__ __launch_bounds__(256) void mlp_kernel(
    float* __restrict__ io,
    const float* __restrict__ g1, const float* __restrict__ b1,
    const float* __restrict__ g2, const float* __restrict__ b2,
    const float* __restrict__ fc1_w, const float* __restrict__ fc1_b,
    const float* __restrict__ fc2_w, const float* __restrict__ fc2_b)
{
    __shared__ float xr[TOK * 97];    // x2' rows (post first residual)
    __shared__ float yb[TOK * 97];    // LN2 rows
    __shared__ float hb[TOK * 385];   // gelu(fc1)
    __shared__ float mu[TOK], rs[TOK], mu2[TOK], rs2[TOK];

    const int tid = threadIdx.x;
    float* base = io + (size_t)blockIdx.x * TOK * C_;

    for (int idx = tid; idx < TOK * C_; idx += 256) {
        int t = idx / C_, c = idx - t * C_;
        xr[t * 97 + c] = base[idx];
    }
    __syncthreads();

    // stats over raw x2 (each wave handles 4 tokens)
    {
        int w = tid >> 6, l = tid & 63;
        for (int i = 0; i < 4; ++i) {
            int t = w * 4 + i;
            float a  = xr[t * 97 + l];
            float bq = (l < 32) ? xr[t * 97 + 64 + l] : 0.f;
            float s1 = a + bq, s2 = a * a + bq * bq;
            #pragma unroll
            for (int off = 32; off; off >>= 1) {
                s1 += __shfl_down(s1, off);
                s2 += __shfl_down(s2, off);
            }
            if (l == 0) {
                float m_ = s1 * (1.f / 96.f);
                mu[t] = m_;
                rs[t] = rsqrtf(s2 * (1.f / 96.f) - m_ * m_ + 1e-5f);
            }
        }
    }
    __syncthreads();

    // x2' = x2 + LN1(x2)
    for (int idx = tid; idx < TOK * C_; idx += 256) {
        int t = idx / C_, c = idx - t * C_;
        float v = xr[t * 97 + c];
        xr[t * 97 + c] = v + (v - mu[t]) * rs[t] * g1[c] + b1[c];
    }
    __syncthreads();

    // stats over x2'
    {
        int w = tid >> 6, l = tid & 63;
        for (int i = 0; i < 4; ++i) {
            int t = w * 4 + i;
            float a  = xr[t * 97 + l];
            float bq = (l < 32) ? xr[t * 97 + 64 + l] : 0.f;
            float s1 = a + bq, s2 = a * a + bq * bq;
            #pragma unroll
            for (int off = 32; off; off >>= 1) {
                s1 += __shfl_down(s1, off);
                s2 += __shfl_down(s2, off);
            }
            if (l == 0) {
                float m_ = s1 * (1.f / 96.f);
                mu2[t] = m_;
                rs2[t] = rsqrtf(s2 * (1.f / 96.f) - m_ * m_ + 1e-5f);
            }
        }
    }
    __syncthreads();

    // y = LN2(x2')
    for (int idx = tid; idx < TOK * C_; idx += 256) {
        int t = idx / C_, c = idx - t * C_;
        yb[t * 97 + c] = (xr[t * 97 + c] - mu2[t]) * rs2[t] * g2[c] + b2[c];
    }
    __syncthreads();

    // fc1 + exact gelu; weight element hoisted across the 16-token batch
    for (int j = tid; j < HID; j += 256) {
        float acc[TOK];
        float bj = fc1_b[j];
        #pragma unroll
        for (int t = 0; t < TOK; ++t) acc[t] = bj;
        for (int k = 0; k < C_; ++k) {
            float wv = fc1_w[k * HID + j];
            #pragma unroll
            for (int t = 0; t < TOK; ++t) acc[t] += yb[t * 97 + k] * wv;
        }
        #pragma unroll
        for (int t = 0; t < TOK; ++t) {
            float a = acc[t];
            hb[t * 385 + j] = 0.5f * a * (1.f + erff(a * 0.70710678118654752f));
        }
    }
    __syncthreads();

    // fc2 + residual; 2 groups x 96 cols, 8 tokens each
    {
        int g = tid / 96;
        int c = tid - g * 96;
        if (g < 2) {
            float acc[8];
            float bc = fc2_b[c];
            #pragma unroll
            for (int t = 0; t < 8; ++t) acc[t] = bc;
            for (int k = 0; k < HID; ++k) {
                float wv = fc2_w[k * 96 + c];
                #pragma unroll
                for (int t = 0; t < 8; ++t) acc[t] += hb[(g * 8 + t) * 385 + k] * wv;
            }
            #pragma unroll
            for (int t = 0; t < 8; ++t) {
                int tt = g * 8 + t;
                base[tt * 96 + c] = xr[tt * 97 + c] + acc[t];
            }
        }
    }
}

// =====================================================================
extern "C" void kernel_launch(void* const* d_in, const int* in_sizes, int n_in,
                              void* d_out, int out_size, void* d_ws, size_t ws_size,
                              hipStream_t stream)
{
    (void)in_sizes; (void)n_in; (void)out_size; (void)d_ws; (void)ws_size;

    const float* x      = (const float*)d_in[0];
    const float* qkv_w  = (const float*)d_in[1];
    const float* qkv_b  = (const float*)d_in[2];
    const float* proj_w = (const float*)d_in[3];
    const float* proj_b = (const float*)d_in[4];
    const float* g1     = (const float*)d_in[5];
    const float* b1     = (const float*)d_in[6];
    const float* g2     = (const float*)d_in[7];
    const float* b2     = (const float*)d_in[8];
    const float* fc1_w  = (const float*)d_in[9];
    const float* fc1_b  = (const float*)d_in[10];
    const float* fc2_w  = (const float*)d_in[11];
    const float* fc2_b  = (const float*)d_in[12];
    float* out = (float*)d_out;

    attn_win_kernel<<<BW, 640, 0, stream>>>(x, qkv_w, qkv_b, proj_w, proj_b, out);
    mlp_kernel<<<NTOK / TOK, 256, 0, stream>>>(out, g1, b1, g2, b2,
                                               fc1_w, fc1_b, fc2_w, fc2_b);
}

// Round 3
// 834.792 us; speedup vs baseline: 3.4989x; 3.4989x over previous
//
#include <hip/hip_runtime.h>
#include <hip/hip_bf16.h>

// ---- problem constants ----
#define B_     16
#define NBAND  4
#define HP     56
#define WP     56
#define C_     96
#define NHEADS 3
#define HD     32
#define NT     196                 // tokens per window
#define NTP    224                 // padded to 14x16
#define BW     1024                // windows
#define HID    384
#define NTOK   200704

typedef unsigned short u16;
typedef short s16;
typedef __attribute__((ext_vector_type(8))) s16   short8_t;  // 8 bf16 (4 VGPR)
typedef __attribute__((ext_vector_type(4))) float f32x4;

__device__ __forceinline__ float bf2f(u16 u) {
    union { float f; unsigned int i; } x; x.i = ((unsigned int)u) << 16; return x.f;
}
__device__ __forceinline__ u16 f2bf(float f) {
    union { float f; unsigned int i; } x; x.f = f;
    unsigned int r = x.i + 0x7fffu + ((x.i >> 16) & 1u);
    return (u16)(r >> 16);
}

// ---- workspace layout (bf16 elements) ----
#define WT_OFF   0          // qkv_w^T  [288][96]
#define PJT_OFF  27648      // proj_w^T [96][96]
#define F1T_OFF  36864      // fc1_w^T  [384][96]
#define F2T_OFF  73728      // fc2_w^T  [96][384]
#define WS_ELEMS 110592     // * 2 bytes = 221,184 B

__global__ __launch_bounds__(256) void setup_kernel(
    const float* __restrict__ qkv_w, const float* __restrict__ proj_w,
    const float* __restrict__ fc1_w, const float* __restrict__ fc2_w,
    u16* __restrict__ ws)
{
    int i0 = blockIdx.x * 256 + threadIdx.x;
    int stride = gridDim.x * 256;
    for (int e = i0; e < 27648; e += stride) {          // wT[n][k] = qkv_w[k][n]
        int n = e / 96, k = e - n * 96;
        ws[WT_OFF + e] = f2bf(qkv_w[k * 288 + n]);
    }
    for (int e = i0; e < 9216; e += stride) {           // pjT[n][k]
        int n = e / 96, k = e - n * 96;
        ws[PJT_OFF + e] = f2bf(proj_w[k * 96 + n]);
    }
    for (int e = i0; e < 36864; e += stride) {          // f1T[n][k], n<384
        int n = e / 96, k = e - n * 96;
        ws[F1T_OFF + e] = f2bf(fc1_w[k * 384 + n]);
    }
    for (int e = i0; e < 36864; e += stride) {          // f2T[n][k], n<96, k<384
        int n = e / 384, k = e - n * 384;
        ws[F2T_OFF + e] = f2bf(fc2_w[k * 96 + n]);
    }
}

// =====================================================================
// MFMA attention kernel: one block per window, 4 waves
// =====================================================================
#define QK_LD 40    // Q/K row stride (u16): 80B -> 2-way bank alias (free)
#define VT_LD 232   // V^T row stride
#define P_LD  232
#define O_LD  104

__global__ __launch_bounds__(256) void attn_mfma_kernel(
    const float* __restrict__ x,
    const u16*  __restrict__ ws,
    const float* __restrict__ qkv_b,
    const float* __restrict__ proj_b,
    float* __restrict__ out)
{
    __shared__ __align__(16) u16 Qs[NTP * QK_LD];      // 17,920 B
    __shared__ __align__(16) u16 Ks[NTP * QK_LD];      // 17,920 B
    __shared__ __align__(16) u16 VTs[HD * VT_LD];      // 14,848 B
    __shared__ __align__(16) u16 Ps[4 * 16 * P_LD];    // 29,696 B
    __shared__ __align__(16) u16 Os[NTP * O_LD];       // 46,592 B
    __shared__ int rowsL[NT];

    const int wi  = blockIdx.x;
    const int b   = wi >> 6, ih = (wi >> 3) & 7, iw = wi & 7;
    const int tid = threadIdx.x;
    const int w   = tid >> 6, lane = tid & 63;
    const int l15 = lane & 15, g = lane >> 4;

    // phase 0: token -> flat row map (roll(-3) gather == roll(+3) scatter)
    if (tid < NT) {
        int t = tid;
        int n = t / 49, rc = t - n * 49, r = rc / 7, cl = rc - r * 7;
        int hh = ih * 7 + r  + 3; if (hh >= HP) hh -= HP;
        int ww = iw * 7 + cl + 3; if (ww >= WP) ww -= WP;
        rowsL[t] = ((b * NBAND + n) * HP + hh) * WP + ww;
    }
    __syncthreads();

    const u16* wT  = ws + WT_OFF;
    const u16* pjT = ws + PJT_OFF;

    for (int h = 0; h < NHEADS; ++h) {
        // ---- QKV GEMM for head h: 84 tasks = (mt,mat,nhalf), 21 per wave ----
        {
            int prev_mt = -1;
            short8_t ax[3];
            for (int i = 0; i < 21; ++i) {
                int tt = w * 21 + i;
                int mt = tt / 6, nj = tt % 6;
                int mat = nj >> 1, nh = nj & 1;
                if (mt != prev_mt) {
                    prev_mt = mt;
                    int t = mt * 16 + l15;
                    bool valid = (t < NT);
                    const float* xb = x + (valid ? (size_t)rowsL[t] * C_ : 0);
                    #pragma unroll
                    for (int ks = 0; ks < 3; ++ks) {
                        short8_t a;
                        if (valid) {
                            const float* p = xb + ks * 32 + g * 8;
                            #pragma unroll
                            for (int j = 0; j < 8; ++j) a[j] = (s16)f2bf(p[j]);
                        } else {
                            #pragma unroll
                            for (int j = 0; j < 8; ++j) a[j] = 0;
                        }
                        ax[ks] = a;
                    }
                }
                int ncol = mat * 96 + h * 32 + nh * 16 + l15;   // col in qkv_w
                f32x4 acc = {0.f, 0.f, 0.f, 0.f};
                #pragma unroll
                for (int ks = 0; ks < 3; ++ks) {
                    short8_t bw = *(const short8_t*)(wT + ncol * 96 + ks * 32 + g * 8);
                    acc = __builtin_amdgcn_mfma_f32_16x16x32_bf16(ax[ks], bw, acc, 0, 0, 0);
                }
                float bias = qkv_b[ncol];
                int d    = nh * 16 + l15;     // 0..31 within head
                int trow = mt * 16 + 4 * g;
                if (mat == 0) {
                    const float sc = 0.17677669529663687f;      // hd^-0.5
                    #pragma unroll
                    for (int r = 0; r < 4; ++r)
                        Qs[(trow + r) * QK_LD + d] = f2bf((acc[r] + bias) * sc);
                } else if (mat == 1) {
                    #pragma unroll
                    for (int r = 0; r < 4; ++r)
                        Ks[(trow + r) * QK_LD + d] = f2bf(acc[r] + bias);
                } else {                       // V: store transposed
                    #pragma unroll
                    for (int r = 0; r < 4; ++r)
                        VTs[d * VT_LD + trow + r] = f2bf(acc[r] + bias);
                }
            }
        }
        __syncthreads();

        // ---- attention: wave handles M-tiles mt = w, w+4, ... ----
        for (int mt = w; mt < 14; mt += 4) {
            short8_t aQ = *(const short8_t*)(Qs + (mt * 16 + l15) * QK_LD + g * 8);
            f32x4 s[13];
            #pragma unroll
            for (int kt = 0; kt < 13; ++kt) {
                short8_t bK = *(const short8_t*)(Ks + (kt * 16 + l15) * QK_LD + g * 8);
                f32x4 z = {0.f, 0.f, 0.f, 0.f};
                s[kt] = __builtin_amdgcn_mfma_f32_16x16x32_bf16(aQ, bK, z, 0, 0, 0);
            }
            if (l15 >= 4) {                   // keys 192+l15 >= 196 invalid
                #pragma unroll
                for (int r = 0; r < 4; ++r) s[12][r] = -1e30f;
            }
            float m[4], sum[4];
            #pragma unroll
            for (int r = 0; r < 4; ++r) {
                float mm = s[0][r];
                #pragma unroll
                for (int kt = 1; kt < 13; ++kt) mm = fmaxf(mm, s[kt][r]);
                #pragma unroll
                for (int o = 1; o < 16; o <<= 1) mm = fmaxf(mm, __shfl_xor(mm, o, 64));
                m[r] = mm;
                sum[r] = 0.f;
            }
            u16* Pw = Ps + w * 16 * P_LD;
            #pragma unroll
            for (int kt = 0; kt < 13; ++kt) {
                #pragma unroll
                for (int r = 0; r < 4; ++r) {
                    float p = __expf(s[kt][r] - m[r]);
                    sum[r] += p;
                    Pw[(4 * g + r) * P_LD + kt * 16 + l15] = f2bf(p);
                }
            }
            #pragma unroll
            for (int r = 0; r < 4; ++r)       // zero padded key tile 13
                Pw[(4 * g + r) * P_LD + 208 + l15] = 0;
            #pragma unroll
            for (int r = 0; r < 4; ++r) {
                #pragma unroll
                for (int o = 1; o < 16; o <<= 1) sum[r] += __shfl_xor(sum[r], o, 64);
            }

            // PV: O(16x32) = P(16x224) @ V(224x32), 7 k-steps
            f32x4 o0 = {0.f,0.f,0.f,0.f}, o1 = {0.f,0.f,0.f,0.f};
            #pragma unroll
            for (int kp = 0; kp < 7; ++kp) {
                short8_t aP  = *(const short8_t*)(Pw + l15 * P_LD + kp * 32 + g * 8);
                short8_t bV0 = *(const short8_t*)(VTs + l15 * VT_LD + kp * 32 + g * 8);
                short8_t bV1 = *(const short8_t*)(VTs + (16 + l15) * VT_LD + kp * 32 + g * 8);
                o0 = __builtin_amdgcn_mfma_f32_16x16x32_bf16(aP, bV0, o0, 0, 0, 0);
                o1 = __builtin_amdgcn_mfma_f32_16x16x32_bf16(aP, bV1, o1, 0, 0, 0);
            }
            int trow = mt * 16 + 4 * g;
            #pragma unroll
            for (int r = 0; r < 4; ++r) {
                float inv = 1.f / sum[r];
                Os[(trow + r) * O_LD + h * 32 + l15]      = f2bf(o0[r] * inv);
                Os[(trow + r) * O_LD + h * 32 + 16 + l15] = f2bf(o1[r] * inv);
            }
        }
        __syncthreads();
    }

    // ---- proj: 84 tasks, 21 per wave; scatter to out ----
    {
        int prev_mt = -1;
        short8_t aO[3];
        for (int i = 0; i < 21; ++i) {
            int tt = w * 21 + i;
            int mt = tt / 6, nj = tt % 6;
            if (mt != prev_mt) {
                prev_mt = mt;
                #pragma unroll
                for (int ks = 0; ks < 3; ++ks)
                    aO[ks] = *(const short8_t*)(Os + (mt * 16 + l15) * O_LD + ks * 32 + g * 8);
            }
            int ncol = nj * 16 + l15;
            f32x4 acc = {0.f, 0.f, 0.f, 0.f};
            #pragma unroll
            for (int ks = 0; ks < 3; ++ks) {
                short8_t bw = *(const short8_t*)(pjT + ncol * 96 + ks * 32 + g * 8);
                acc = __builtin_amdgcn_mfma_f32_16x16x32_bf16(aO[ks], bw, acc, 0, 0, 0);
            }
            float bias = proj_b[ncol];
            int trow = mt * 16 + 4 * g;
            #pragma unroll
            for (int r = 0; r < 4; ++r) {
                int t = trow + r;
                if (t < NT) out[(size_t)rowsL[t] * C_ + ncol] = acc[r] + bias;
            }
        }
    }
}

// =====================================================================
// MFMA MLP kernel: 64 tokens per block, 4 waves (wave w owns M-tile w)
// =====================================================================
__global__ __launch_bounds__(256) void mlp_mfma_kernel(
    float* __restrict__ io,
    const u16* __restrict__ ws,
    const float* __restrict__ g1, const float* __restrict__ b1,
    const float* __restrict__ g2, const float* __restrict__ b2,
    const float* __restrict__ fc1_b, const float* __restrict__ fc2_b)
{
    __shared__ float xr[64 * 97];                       // 24,832 B (x2' fp32)
    __shared__ __align__(16) u16 yb[64 * 104];          // 13,312 B (LN2, bf16)
    __shared__ __align__(16) u16 hb[64 * 392];          // 50,176 B (gelu(fc1))
    __shared__ float mu[64], rs[64], mu2[64], rs2[64];

    const int tid = threadIdx.x;
    const int w = tid >> 6, lane = tid & 63, l15 = lane & 15, g = lane >> 4;
    float* base = io + (size_t)blockIdx.x * 64 * C_;
    const u16* f1T = ws + F1T_OFF;
    const u16* f2T = ws + F2T_OFF;

    for (int i = tid; i < 64 * 96; i += 256) {
        int t = i / 96, c = i - t * 96;
        xr[t * 97 + c] = base[i];
    }
    __syncthreads();

    // LN1 stats
    for (int i = 0; i < 16; ++i) {
        int t = w * 16 + i;
        float a  = xr[t * 97 + lane];
        float bq = (lane < 32) ? xr[t * 97 + 64 + lane] : 0.f;
        float s1 = a + bq, s2 = a * a + bq * bq;
        #pragma unroll
        for (int off = 32; off; off >>= 1) {
            s1 += __shfl_down(s1, off);
            s2 += __shfl_down(s2, off);
        }
        if (lane == 0) {
            float m_ = s1 * (1.f / 96.f);
            mu[t] = m_;
            rs[t] = rsqrtf(s2 * (1.f / 96.f) - m_ * m_ + 1e-5f);
        }
    }
    __syncthreads();
    // x2' = x2 + LN1(x2)
    for (int i = tid; i < 64 * 96; i += 256) {
        int t = i / 96, c = i - t * 96;
        float v = xr[t * 97 + c];
        xr[t * 97 + c] = v + (v - mu[t]) * rs[t] * g1[c] + b1[c];
    }
    __syncthreads();
    // LN2 stats
    for (int i = 0; i < 16; ++i) {
        int t = w * 16 + i;
        float a  = xr[t * 97 + lane];
        float bq = (lane < 32) ? xr[t * 97 + 64 + lane] : 0.f;
        float s1 = a + bq, s2 = a * a + bq * bq;
        #pragma unroll
        for (int off = 32; off; off >>= 1) {
            s1 += __shfl_down(s1, off);
            s2 += __shfl_down(s2, off);
        }
        if (lane == 0) {
            float m_ = s1 * (1.f / 96.f);
            mu2[t] = m_;
            rs2[t] = rsqrtf(s2 * (1.f / 96.f) - m_ * m_ + 1e-5f);
        }
    }
    __syncthreads();
    for (int i = tid; i < 64 * 96; i += 256) {
        int t = i / 96, c = i - t * 96;
        yb[t * 104 + c] = f2bf((xr[t * 97 + c] - mu2[t]) * rs2[t] * g2[c] + b2[c]);
    }
    __syncthreads();

    // fc1 + gelu: wave w -> M-tile w, 24 N-tiles
    {
        short8_t aY[3];
        #pragma unroll
        for (int ks = 0; ks < 3; ++ks)
            aY[ks] = *(const short8_t*)(yb + (w * 16 + l15) * 104 + ks * 32 + g * 8);
        for (int nt = 0; nt < 24; ++nt) {
            int ncol = nt * 16 + l15;
            f32x4 acc = {0.f, 0.f, 0.f, 0.f};
            #pragma unroll
            for (int ks = 0; ks < 3; ++ks) {
                short8_t bw = *(const short8_t*)(f1T + ncol * 96 + ks * 32 + g * 8);
                acc = __builtin_amdgcn_mfma_f32_16x16x32_bf16(aY[ks], bw, acc, 0, 0, 0);
            }
            float bias = fc1_b[ncol];
            int trow = w * 16 + 4 * g;
            #pragma unroll
            for (int r = 0; r < 4; ++r) {
                float a_ = acc[r] + bias;
                float gl = 0.5f * a_ * (1.f + erff(a_ * 0.70710678118654752f));
                hb[(trow + r) * 392 + ncol] = f2bf(gl);
            }
        }
    }
    __syncthreads();

    // fc2 + residual: wave w -> M-tile w, 6 N-tiles, 12 k-steps
    {
        short8_t aH[12];
        #pragma unroll
        for (int ks = 0; ks < 12; ++ks)
            aH[ks] = *(const short8_t*)(hb + (w * 16 + l15) * 392 + ks * 32 + g * 8);
        for (int nj = 0; nj < 6; ++nj) {
            int ncol = nj * 16 + l15;
            f32x4 acc = {0.f, 0.f, 0.f, 0.f};
            #pragma unroll
            for (int ks = 0; ks < 12; ++ks) {
                short8_t bw = *(const short8_t*)(f2T + ncol * 384 + ks * 32 + g * 8);
                acc = __builtin_amdgcn_mfma_f32_16x16x32_bf16(aH[ks], bw, acc, 0, 0, 0);
            }
            float bias = fc2_b[ncol];
            int trow = w * 16 + 4 * g;
            #pragma unroll
            for (int r = 0; r < 4; ++r) {
                int t = trow + r;
                base[t * 96 + ncol] = xr[t * 97 + ncol] + acc[r] + bias;
            }
        }
    }
}

// =====================================================================
// Fallback (round-1 VALU kernels) if ws is too small for weight transposes
// =====================================================================
#define KV_LD 200
#define XS_LD 98

__global__ __launch_bounds__(640) void attn_win_kernel(
    const float* __restrict__ x,
    const float* __restrict__ qkv_w, const float* __restrict__ qkv_b,
    const float* __restrict__ proj_w, const float* __restrict__ proj_b,
    float* __restrict__ out)
{
    __shared__ __align__(16) u16 kv[NT * KV_LD];
    __shared__ u16 xs[NT * XS_LD];
    const int wi = blockIdx.x;
    const int b = wi >> 6, ih = (wi >> 3) & 7, iw = wi & 7;
    const int tid = threadIdx.x;
    auto rowOf = [&](int t) -> int {
        int n = t / 49, rc = t - n * 49, r = rc / 7, cl = rc - r * 7;
        int hh = ih * 7 + r + 3; if (hh >= HP) hh -= HP;
        int ww = iw * 7 + cl + 3; if (ww >= WP) ww -= WP;
        return ((b * NBAND + n) * HP + hh) * WP + ww;
    };
    for (int idx = tid; idx < NT * C_; idx += 640) {
        int t = idx / C_, c = idx - t * C_;
        xs[t * XS_LD + c] = f2bf(x[(size_t)rowOf(t) * C_ + c]);
    }
    __syncthreads();
    for (int idx = tid; idx < NT * 192; idx += 640) {
        int t = idx / 192, c = idx - t * 192, qc = 96 + c;
        float acc = qkv_b[qc];
        for (int k = 0; k < C_; ++k)
            acc += bf2f(xs[t * XS_LD + k]) * qkv_w[k * 288 + qc];
        kv[t * KV_LD + c] = f2bf(acc);
    }
    __syncthreads();
    float o[HD]; int pt = -1, ph = 0;
    if (tid < NT * NHEADS) {
        pt = tid % NT; ph = tid / NT;
        const int qb = ph * HD;
        float q[HD];
        #pragma unroll
        for (int d = 0; d < HD; ++d) q[d] = qkv_b[qb + d];
        for (int k = 0; k < C_; ++k) {
            float xk = bf2f(xs[pt * XS_LD + k]);
            const float* wr = qkv_w + k * 288 + qb;
            #pragma unroll
            for (int d = 0; d < HD; ++d) q[d] += xk * wr[d];
        }
        #pragma unroll
        for (int d = 0; d < HD; ++d) q[d] *= 0.17677669529663687f;
        float m = -1e30f;
        for (int kk = 0; kk < NT; ++kk) {
            float s = 0.f;
            for (int c = 0; c < HD; ++c) s += q[c] * bf2f(kv[kk * KV_LD + qb + c]);
            m = fmaxf(m, s);
        }
        float sum = 0.f;
        #pragma unroll
        for (int d = 0; d < HD; ++d) o[d] = 0.f;
        for (int kk = 0; kk < NT; ++kk) {
            float s = 0.f;
            for (int c = 0; c < HD; ++c) s += q[c] * bf2f(kv[kk * KV_LD + qb + c]);
            float p = __expf(s - m); sum += p;
            for (int d = 0; d < HD; ++d) o[d] += p * bf2f(kv[kk * KV_LD + 96 + qb + d]);
        }
        float inv = 1.f / sum;
        #pragma unroll
        for (int d = 0; d < HD; ++d) o[d] *= inv;
    }
    __syncthreads();
    if (pt >= 0)
        for (int d = 0; d < HD; ++d) kv[pt * KV_LD + ph * HD + d] = f2bf(o[d]);
    __syncthreads();
    for (int idx = tid; idx < NT * C_; idx += 640) {
        int t = idx / 96, c = idx - t * 96;
        float acc = proj_b[c];
        for (int k = 0; k < C_; ++k)
            acc += bf2f(kv[t * KV_LD + k]) * proj_w[k * 96 + c];
        out[(size_t)rowOf(t) * C_ + c] = acc;
    }
}

__global__ __launch_bounds__(256) void mlp_kernel(
    float* __restrict__ io,
    const float* __restrict__ g1, const float* __restrict__ b1,
    const float* __restrict__ g2, const float* __restrict__ b2,
    const float* __restrict__ fc1_w, const float* __restrict__ fc1_b,
    const float* __restrict__ fc2_w, const float* __restrict__ fc2_b)
{
    __shared__ float xr[16 * 97], yb2[16 * 97], hb2[16 * 385];
    __shared__ float mu[16], rs[16], mu2[16], rs2[16];
    const int tid = threadIdx.x;
    float* base = io + (size_t)blockIdx.x * 16 * C_;
    for (int i = tid; i < 16 * 96; i += 256) { int t = i / 96, c = i - t * 96; xr[t * 97 + c] = base[i]; }
    __syncthreads();
    {
        int w = tid >> 6, l = tid & 63;
        for (int i = 0; i < 4; ++i) {
            int t = w * 4 + i;
            float a = xr[t * 97 + l], bq = (l < 32) ? xr[t * 97 + 64 + l] : 0.f;
            float s1 = a + bq, s2 = a * a + bq * bq;
            #pragma unroll
            for (int off = 32; off; off >>= 1) { s1 += __shfl_down(s1, off); s2 += __shfl_down(s2, off); }
            if (l == 0) { float m_ = s1 / 96.f; mu[t] = m_; rs[t] = rsqrtf(s2 / 96.f - m_ * m_ + 1e-5f); }
        }
    }
    __syncthreads();
    for (int i = tid; i < 16 * 96; i += 256) {
        int t = i / 96, c = i - t * 96;
        float v = xr[t * 97 + c];
        xr[t * 97 + c] = v + (v - mu[t]) * rs[t] * g1[c] + b1[c];
    }
    __syncthreads();
    {
        int w = tid >> 6, l = tid & 63;
        for (int i = 0; i < 4; ++i) {
            int t = w * 4 + i;
            float a = xr[t * 97 + l], bq = (l < 32) ? xr[t * 97 + 64 + l] : 0.f;
            float s1 = a + bq, s2 = a * a + bq * bq;
            #pragma unroll
            for (int off = 32; off; off >>= 1) { s1 += __shfl_down(s1, off); s2 += __shfl_down(s2, off); }
            if (l == 0) { float m_ = s1 / 96.f; mu2[t] = m_; rs2[t] = rsqrtf(s2 / 96.f - m_ * m_ + 1e-5f); }
        }
    }
    __syncthreads();
    for (int i = tid; i < 16 * 96; i += 256) {
        int t = i / 96, c = i - t * 96;
        yb2[t * 97 + c] = (xr[t * 97 + c] - mu2[t]) * rs2[t] * g2[c] + b2[c];
    }
    __syncthreads();
    for (int j = tid; j < HID; j += 256) {
        float acc[16]; float bj = fc1_b[j];
        #pragma unroll
        for (int t = 0; t < 16; ++t) acc[t] = bj;
        for (int k = 0; k < C_; ++k) {
            float wv = fc1_w[k * HID + j];
            #pragma unroll
            for (int t = 0; t < 16; ++t) acc[t] += yb2[t * 97 + k] * wv;
        }
        #pragma unroll
        for (int t = 0; t < 16; ++t) {
            float a = acc[t];
            hb2[t * 385 + j] = 0.5f * a * (1.f + erff(a * 0.70710678118654752f));
        }
    }
    __syncthreads();
    {
        int gq = tid / 96, c = tid - gq * 96;
        if (gq < 2) {
            float acc[8]; float bc = fc2_b[c];
            #pragma unroll
            for (int t = 0; t < 8; ++t) acc[t] = bc;
            for (int k = 0; k < HID; ++k) {
                float wv = fc2_w[k * 96 + c];
                #pragma unroll
                for (int t = 0; t < 8; ++t) acc[t] += hb2[(gq * 8 + t) * 385 + k] * wv;
            }
            #pragma unroll
            for (int t = 0; t < 8; ++t) {
                int tt = gq * 8 + t;
                base[tt * 96 + c] = xr[tt * 97 + c] + acc[t];
            }
        }
    }
}

// =====================================================================
extern "C" void kernel_launch(void* const* d_in, const int* in_sizes, int n_in,
                              void* d_out, int out_size, void* d_ws, size_t ws_size,
                              hipStream_t stream)
{
    (void)in_sizes; (void)n_in; (void)out_size;

    const float* x      = (const float*)d_in[0];
    const float* qkv_w  = (const float*)d_in[1];
    const float* qkv_b  = (const float*)d_in[2];
    const float* proj_w = (const float*)d_in[3];
    const float* proj_b = (const float*)d_in[4];
    const float* g1     = (const float*)d_in[5];
    const float* b1     = (const float*)d_in[6];
    const float* g2     = (const float*)d_in[7];
    const float* b2     = (const float*)d_in[8];
    const float* fc1_w  = (const float*)d_in[9];
    const float* fc1_b  = (const float*)d_in[10];
    const float* fc2_w  = (const float*)d_in[11];
    const float* fc2_b  = (const float*)d_in[12];
    float* out = (float*)d_out;

    if (ws_size >= (size_t)WS_ELEMS * 2) {
        u16* ws = (u16*)d_ws;
        setup_kernel<<<128, 256, 0, stream>>>(qkv_w, proj_w, fc1_w, fc2_w, ws);
        attn_mfma_kernel<<<BW, 256, 0, stream>>>(x, ws, qkv_b, proj_b, out);
        mlp_mfma_kernel<<<NTOK / 64, 256, 0, stream>>>(out, ws, g1, b1, g2, b2, fc1_b, fc2_b);
    } else {
        attn_win_kernel<<<BW, 640, 0, stream>>>(x, qkv_w, qkv_b, proj_w, proj_b, out);
        mlp_kernel<<<NTOK / 16, 256, 0, stream>>>(out, g1, b1, g2, b2,
                                                  fc1_w, fc1_b, fc2_w, fc2_b);
    }
}

// Round 4
// 430.248 us; speedup vs baseline: 6.7887x; 1.9403x over previous
//
#include <hip/hip_runtime.h>
#include <hip/hip_bf16.h>

// ---- problem constants ----
#define B_     16
#define NBAND  4
#define HP     56
#define WP     56
#define C_     96
#define NHEADS 3
#define HD     32
#define NT     196                 // tokens per window
#define NTP    224                 // padded to 14x16
#define BW     1024                // windows
#define HID    384
#define NTOK   200704

typedef unsigned short u16;
typedef short s16;
typedef __attribute__((ext_vector_type(8))) s16   short8_t;  // 8 bf16 (4 VGPR)
typedef __attribute__((ext_vector_type(4))) s16   short4_t;
typedef __attribute__((ext_vector_type(4))) float f32x4;

__device__ __forceinline__ float bf2f(u16 u) {
    union { float f; unsigned int i; } x; x.i = ((unsigned int)u) << 16; return x.f;
}
__device__ __forceinline__ u16 f2bf(float f) {
    union { float f; unsigned int i; } x; x.f = f;
    unsigned int r = x.i + 0x7fffu + ((x.i >> 16) & 1u);
    return (u16)(r >> 16);
}

// ---- workspace layout (bf16 elements) ----
#define WT_OFF   0          // qkv_w^T  [288][96]
#define PJT_OFF  27648      // proj_w^T [96][96]
#define F1T_OFF  36864      // fc1_w^T  [384][96]
#define F2T_OFF  73728      // fc2_w^T  [96][384]
#define WS_ELEMS 110592     // * 2 bytes = 221,184 B

__global__ __launch_bounds__(256) void setup_kernel(
    const float* __restrict__ qkv_w, const float* __restrict__ proj_w,
    const float* __restrict__ fc1_w, const float* __restrict__ fc2_w,
    u16* __restrict__ ws)
{
    int i0 = blockIdx.x * 256 + threadIdx.x;
    int stride = gridDim.x * 256;
    for (int e = i0; e < 27648; e += stride) {          // wT[n][k] = qkv_w[k][n]
        int n = e / 96, k = e - n * 96;
        ws[WT_OFF + e] = f2bf(qkv_w[k * 288 + n]);
    }
    for (int e = i0; e < 9216; e += stride) {           // pjT[n][k]
        int n = e / 96, k = e - n * 96;
        ws[PJT_OFF + e] = f2bf(proj_w[k * 96 + n]);
    }
    for (int e = i0; e < 36864; e += stride) {          // f1T[n][k], n<384
        int n = e / 96, k = e - n * 96;
        ws[F1T_OFF + e] = f2bf(fc1_w[k * 384 + n]);
    }
    for (int e = i0; e < 36864; e += stride) {          // f2T[n][k], n<96, k<384
        int n = e / 384, k = e - n * 384;
        ws[F2T_OFF + e] = f2bf(fc2_w[k * 96 + n]);
    }
}

// =====================================================================
// MFMA attention kernel: one block per window, 8 waves (512 thr)
// per-head proj accumulation in registers; per-wave LDS chunk staging
// =====================================================================
#define QK_LD  40    // Q/K row stride (u16): 80B -> 2-way bank alias (free)
#define VT_LD  232   // V^T row stride
#define STG_LD 40    // per-wave staging row stride

__global__ __launch_bounds__(512) void attn_mfma_kernel(
    const float* __restrict__ x,
    const u16*  __restrict__ ws,
    const float* __restrict__ qkv_b,
    const float* __restrict__ proj_b,
    float* __restrict__ out)
{
    __shared__ __align__(16) u16 Qs[NTP * QK_LD];        // 17,920 B
    __shared__ __align__(16) u16 Ks[NTP * QK_LD];        // 17,920 B
    __shared__ __align__(16) u16 VTs[HD * VT_LD];        // 14,848 B
    __shared__ __align__(16) u16 Stg[8 * 2 * 16 * STG_LD]; // 20,480 B (per-wave ping-pong)
    __shared__ int rowsL[NT];

    const int wi  = blockIdx.x;
    const int b   = wi >> 6, ih = (wi >> 3) & 7, iw = wi & 7;
    const int tid = threadIdx.x;
    const int w   = tid >> 6, lane = tid & 63;
    const int l15 = lane & 15, g = lane >> 4;

    // token t=(n,r,col) -> flat row; roll(-3) gather == roll(+3) scatter
    if (tid < NT) {
        int t = tid;
        int n = t / 49, rc = t - n * 49, r = rc / 7, cl = rc - r * 7;
        int hh = ih * 7 + r  + 3; if (hh >= HP) hh -= HP;
        int ww = iw * 7 + cl + 3; if (ww >= WP) ww -= WP;
        rowsL[t] = ((b * NBAND + n) * HP + hh) * WP + ww;
    }
    __syncthreads();

    const u16* wT  = ws + WT_OFF;
    const u16* pjT = ws + PJT_OFF;

    f32x4 po[2][6];                       // proj accumulators (wave owns <=2 M-tiles)
    #pragma unroll
    for (int im = 0; im < 2; ++im)
        #pragma unroll
        for (int nj = 0; nj < 6; ++nj)
            po[im][nj] = (f32x4){0.f, 0.f, 0.f, 0.f};

    u16* const st0 = Stg + w * (2 * 16 * STG_LD);

    for (int h = 0; h < NHEADS; ++h) {
        // ---- QKV GEMM for head h: wave w handles M-tiles {w, w+8} ----
        for (int mt = w; mt < 14; mt += 8) {
            int t = mt * 16 + l15;
            bool valid = (t < NT);
            const float* xb = x + (valid ? (size_t)rowsL[t] * C_ : 0);
            short8_t ax[3];
            #pragma unroll
            for (int ks = 0; ks < 3; ++ks) {
                short8_t a;
                if (valid) {
                    const float* p = xb + ks * 32 + g * 8;
                    #pragma unroll
                    for (int j = 0; j < 8; ++j) a[j] = (s16)f2bf(p[j]);
                } else {
                    #pragma unroll
                    for (int j = 0; j < 8; ++j) a[j] = 0;
                }
                ax[ks] = a;
            }
            #pragma unroll
            for (int nj = 0; nj < 6; ++nj) {
                int mat = nj >> 1, nh = nj & 1;
                int ncol = mat * 96 + h * 32 + nh * 16 + l15;
                f32x4 acc = {0.f, 0.f, 0.f, 0.f};
                #pragma unroll
                for (int ks = 0; ks < 3; ++ks) {
                    short8_t bw = *(const short8_t*)(wT + ncol * 96 + ks * 32 + g * 8);
                    acc = __builtin_amdgcn_mfma_f32_16x16x32_bf16(ax[ks], bw, acc, 0, 0, 0);
                }
                float bias = qkv_b[ncol];
                int d    = nh * 16 + l15;
                int trow = mt * 16 + 4 * g;
                if (mat == 0) {
                    const float sc = 0.17677669529663687f;      // hd^-0.5 folded into Q
                    #pragma unroll
                    for (int r = 0; r < 4; ++r)
                        Qs[(trow + r) * QK_LD + d] = f2bf((acc[r] + bias) * sc);
                } else if (mat == 1) {
                    #pragma unroll
                    for (int r = 0; r < 4; ++r)
                        Ks[(trow + r) * QK_LD + d] = f2bf(acc[r] + bias);
                } else {                       // V stored transposed, b64 row-writes
                    short4_t v4;
                    #pragma unroll
                    for (int r = 0; r < 4; ++r) v4[r] = (s16)f2bf(acc[r] + bias);
                    *(short4_t*)(VTs + d * VT_LD + trow) = v4;
                }
            }
        }
        __syncthreads();

        // ---- attention + per-head proj accumulate ----
        for (int mt = w, im = 0; mt < 14; mt += 8, ++im) {
            short8_t aQ = *(const short8_t*)(Qs + (mt * 16 + l15) * QK_LD + g * 8);
            f32x4 s[13];
            #pragma unroll
            for (int kt = 0; kt < 13; ++kt) {
                short8_t bK = *(const short8_t*)(Ks + (kt * 16 + l15) * QK_LD + g * 8);
                f32x4 z = {0.f, 0.f, 0.f, 0.f};
                s[kt] = __builtin_amdgcn_mfma_f32_16x16x32_bf16(aQ, bK, z, 0, 0, 0);
            }
            if (l15 >= 4) {                   // keys 192+l15 >= 196 invalid
                #pragma unroll
                for (int r = 0; r < 4; ++r) s[12][r] = -1e30f;
            }
            float m[4], sum[4];
            #pragma unroll
            for (int r = 0; r < 4; ++r) {
                float mm = s[0][r];
                #pragma unroll
                for (int kt = 1; kt < 13; ++kt) mm = fmaxf(mm, s[kt][r]);
                #pragma unroll
                for (int o = 1; o < 16; o <<= 1) mm = fmaxf(mm, __shfl_xor(mm, o, 64));
                m[r] = mm;
                sum[r] = 0.f;
            }

            // PV chunked: per kp stage 16x32 of P, read A-frag, 2 MFMA
            f32x4 o0 = {0.f,0.f,0.f,0.f}, o1 = {0.f,0.f,0.f,0.f};
            #pragma unroll
            for (int kp = 0; kp < 7; ++kp) {
                u16* st = st0 + (kp & 1) * (16 * STG_LD);
                #pragma unroll
                for (int r = 0; r < 4; ++r) {
                    float p0 = __expf(s[2 * kp][r] - m[r]);
                    sum[r] += p0;
                    st[(4 * g + r) * STG_LD + l15] = f2bf(p0);
                    if (kp < 6) {
                        float p1 = __expf(s[2 * kp + 1][r] - m[r]);
                        sum[r] += p1;
                        st[(4 * g + r) * STG_LD + 16 + l15] = f2bf(p1);
                    } else {
                        st[(4 * g + r) * STG_LD + 16 + l15] = 0;   // padded keys 208..223
                    }
                }
                short8_t aP  = *(const short8_t*)(st + l15 * STG_LD + g * 8);
                short8_t bV0 = *(const short8_t*)(VTs + l15 * VT_LD + kp * 32 + g * 8);
                short8_t bV1 = *(const short8_t*)(VTs + (16 + l15) * VT_LD + kp * 32 + g * 8);
                o0 = __builtin_amdgcn_mfma_f32_16x16x32_bf16(aP, bV0, o0, 0, 0, 0);
                o1 = __builtin_amdgcn_mfma_f32_16x16x32_bf16(aP, bV1, o1, 0, 0, 0);
            }
            #pragma unroll
            for (int r = 0; r < 4; ++r) {
                #pragma unroll
                for (int o = 1; o < 16; o <<= 1) sum[r] += __shfl_xor(sum[r], o, 64);
            }

            // normalize, stage O chunk, accumulate proj k-slice for head h
            {
                u16* st = st0;
                #pragma unroll
                for (int r = 0; r < 4; ++r) {
                    float inv = 1.f / sum[r];
                    st[(4 * g + r) * STG_LD + l15]      = f2bf(o0[r] * inv);
                    st[(4 * g + r) * STG_LD + 16 + l15] = f2bf(o1[r] * inv);
                }
                short8_t aO = *(const short8_t*)(st + l15 * STG_LD + g * 8);
                #pragma unroll
                for (int nj = 0; nj < 6; ++nj) {
                    short8_t bw = *(const short8_t*)(pjT + (nj * 16 + l15) * 96 + h * 32 + g * 8);
                    po[im][nj] = __builtin_amdgcn_mfma_f32_16x16x32_bf16(aO, bw, po[im][nj], 0, 0, 0);
                }
            }
        }
        __syncthreads();
    }

    // ---- epilogue: bias + scatter (window-reverse + roll(+3)) ----
    for (int mt = w, im = 0; mt < 14; mt += 8, ++im) {
        int trow = mt * 16 + 4 * g;
        #pragma unroll
        for (int nj = 0; nj < 6; ++nj) {
            int ncol = nj * 16 + l15;
            float bias = proj_b[ncol];
            #pragma unroll
            for (int r = 0; r < 4; ++r) {
                int t = trow + r;
                if (t < NT) out[(size_t)rowsL[t] * C_ + ncol] = po[im][nj][r] + bias;
            }
        }
    }
}

// =====================================================================
// MFMA MLP kernel: 64 tokens/block, 4 waves; fc1->gelu->fc2 fused per
// k-chunk through per-wave LDS staging (no big hb buffer)
// =====================================================================
__global__ __launch_bounds__(256) void mlp_mfma_kernel(
    float* __restrict__ io,
    const u16* __restrict__ ws,
    const float* __restrict__ g1, const float* __restrict__ b1,
    const float* __restrict__ g2, const float* __restrict__ b2,
    const float* __restrict__ fc1_b, const float* __restrict__ fc2_b)
{
    __shared__ float xr[64 * 100];                      // 25,600 B (x2' fp32)
    __shared__ __align__(16) u16 yb[64 * 104];          // 13,312 B (LN2, bf16)
    __shared__ __align__(16) u16 stage[4 * 2 * 16 * STG_LD];  // 10,240 B
    __shared__ float mu[64], rs[64], mu2[64], rs2[64];

    const int tid = threadIdx.x;
    const int w = tid >> 6, l15 = (tid & 63) & 15, g = (tid & 63) >> 4;
    float* base = io + (size_t)blockIdx.x * 64 * C_;
    const u16* f1T = ws + F1T_OFF;
    const u16* f2T = ws + F2T_OFF;

    for (int i = tid; i < 64 * 96; i += 256) {
        int t = i / 96, c = i - t * 96;
        xr[t * 100 + c] = base[i];
    }
    __syncthreads();

    // LN1 stats: 4 lanes per token, 24 elems each
    {
        int t = tid >> 2, q = tid & 3;
        const float* row = xr + t * 100 + q * 24;
        float s1 = 0.f, s2 = 0.f;
        #pragma unroll
        for (int j = 0; j < 24; ++j) { float v = row[j]; s1 += v; s2 += v * v; }
        s1 += __shfl_xor(s1, 1); s2 += __shfl_xor(s2, 1);
        s1 += __shfl_xor(s1, 2); s2 += __shfl_xor(s2, 2);
        if (q == 0) {
            float m_ = s1 * (1.f / 96.f);
            mu[t] = m_;
            rs[t] = rsqrtf(s2 * (1.f / 96.f) - m_ * m_ + 1e-5f);
        }
    }
    __syncthreads();
    // x2' = x2 + LN1(x2)
    for (int i = tid; i < 64 * 96; i += 256) {
        int t = i / 96, c = i - t * 96;
        float v = xr[t * 100 + c];
        xr[t * 100 + c] = v + (v - mu[t]) * rs[t] * g1[c] + b1[c];
    }
    __syncthreads();
    // LN2 stats
    {
        int t = tid >> 2, q = tid & 3;
        const float* row = xr + t * 100 + q * 24;
        float s1 = 0.f, s2 = 0.f;
        #pragma unroll
        for (int j = 0; j < 24; ++j) { float v = row[j]; s1 += v; s2 += v * v; }
        s1 += __shfl_xor(s1, 1); s2 += __shfl_xor(s2, 1);
        s1 += __shfl_xor(s1, 2); s2 += __shfl_xor(s2, 2);
        if (q == 0) {
            float m_ = s1 * (1.f / 96.f);
            mu2[t] = m_;
            rs2[t] = rsqrtf(s2 * (1.f / 96.f) - m_ * m_ + 1e-5f);
        }
    }
    __syncthreads();
    for (int i = tid; i < 64 * 96; i += 256) {
        int t = i / 96, c = i - t * 96;
        yb[t * 104 + c] = f2bf((xr[t * 100 + c] - mu2[t]) * rs2[t] * g2[c] + b2[c]);
    }
    __syncthreads();

    // fused fc1 -> gelu -> fc2 (wave w owns M-tile w)
    short8_t aY[3];
    #pragma unroll
    for (int ks = 0; ks < 3; ++ks)
        aY[ks] = *(const short8_t*)(yb + (w * 16 + l15) * 104 + ks * 32 + g * 8);

    f32x4 po[6];
    #pragma unroll
    for (int nj = 0; nj < 6; ++nj) po[nj] = (f32x4){0.f, 0.f, 0.f, 0.f};

    u16* const st0 = stage + w * (2 * 16 * STG_LD);
    for (int ks = 0; ks < 12; ++ks) {         // fc2 k-step = 2 fc1 N-tiles
        u16* st = st0 + (ks & 1) * (16 * STG_LD);
        #pragma unroll
        for (int half = 0; half < 2; ++half) {
            int ncol = (ks * 2 + half) * 16 + l15;
            f32x4 acc = {0.f, 0.f, 0.f, 0.f};
            #pragma unroll
            for (int k2 = 0; k2 < 3; ++k2) {
                short8_t bw = *(const short8_t*)(f1T + ncol * 96 + k2 * 32 + g * 8);
                acc = __builtin_amdgcn_mfma_f32_16x16x32_bf16(aY[k2], bw, acc, 0, 0, 0);
            }
            float bias = fc1_b[ncol];
            #pragma unroll
            for (int r = 0; r < 4; ++r) {
                float a_ = acc[r] + bias;
                float gl = 0.5f * a_ * (1.f + erff(a_ * 0.70710678118654752f));
                st[(4 * g + r) * STG_LD + half * 16 + l15] = f2bf(gl);
            }
        }
        short8_t aH = *(const short8_t*)(st + l15 * STG_LD + g * 8);
        #pragma unroll
        for (int nj = 0; nj < 6; ++nj) {
            short8_t bw = *(const short8_t*)(f2T + (nj * 16 + l15) * 384 + ks * 32 + g * 8);
            po[nj] = __builtin_amdgcn_mfma_f32_16x16x32_bf16(aH, bw, po[nj], 0, 0, 0);
        }
    }

    // epilogue: residual + bias
    {
        int trow = w * 16 + 4 * g;
        #pragma unroll
        for (int nj = 0; nj < 6; ++nj) {
            int ncol = nj * 16 + l15;
            float bias = fc2_b[ncol];
            #pragma unroll
            for (int r = 0; r < 4; ++r) {
                int t = trow + r;
                base[t * 96 + ncol] = xr[t * 100 + ncol] + po[nj][r] + bias;
            }
        }
    }
}

// =====================================================================
extern "C" void kernel_launch(void* const* d_in, const int* in_sizes, int n_in,
                              void* d_out, int out_size, void* d_ws, size_t ws_size,
                              hipStream_t stream)
{
    (void)in_sizes; (void)n_in; (void)out_size; (void)ws_size;

    const float* x      = (const float*)d_in[0];
    const float* qkv_w  = (const float*)d_in[1];
    const float* qkv_b  = (const float*)d_in[2];
    const float* proj_w = (const float*)d_in[3];
    const float* proj_b = (const float*)d_in[4];
    const float* g1     = (const float*)d_in[5];
    const float* b1     = (const float*)d_in[6];
    const float* g2     = (const float*)d_in[7];
    const float* b2     = (const float*)d_in[8];
    const float* fc1_b  = (const float*)d_in[10];
    const float* fc2_b  = (const float*)d_in[12];
    const float* fc1_w  = (const float*)d_in[9];
    const float* fc2_w  = (const float*)d_in[11];
    float* out = (float*)d_out;
    u16* ws = (u16*)d_ws;

    setup_kernel<<<128, 256, 0, stream>>>(qkv_w, proj_w, fc1_w, fc2_w, ws);
    attn_mfma_kernel<<<BW, 512, 0, stream>>>(x, ws, qkv_b, proj_b, out);
    mlp_mfma_kernel<<<NTOK / 64, 256, 0, stream>>>(out, ws, g1, b1, g2, b2, fc1_b, fc2_b);
}

// Round 5
// 388.304 us; speedup vs baseline: 7.5220x; 1.1080x over previous
//
#include <hip/hip_runtime.h>
#include <hip/hip_bf16.h>

// ---- problem constants ----
#define B_     16
#define NBAND  4
#define HP     56
#define WP     56
#define C_     96
#define NHEADS 3
#define HD     32
#define NT     196                 // tokens per window
#define NTP    224                 // padded to 14x16
#define BW     1024                // windows
#define HID    384
#define NTOK   200704

typedef unsigned short u16;
typedef short s16;
typedef __attribute__((ext_vector_type(8))) s16   short8_t;  // 8 bf16 (4 VGPR)
typedef __attribute__((ext_vector_type(4))) s16   short4_t;
typedef __attribute__((ext_vector_type(4))) float f32x4;

__device__ __forceinline__ float bf2f(u16 u) {
    union { float f; unsigned int i; } x; x.i = ((unsigned int)u) << 16; return x.f;
}
__device__ __forceinline__ u16 f2bf(float f) {
    union { float f; unsigned int i; } x; x.f = f;
    unsigned int r = x.i + 0x7fffu + ((x.i >> 16) & 1u);
    return (u16)(r >> 16);
}
// exact-GELU via A&S 7.1.26 erf approximation (max err 1.5e-7)
__device__ __forceinline__ float gelu_f(float a) {
    float x  = a * 0.70710678118654752f;
    float ax = fabsf(x);
    float t  = 1.0f / (1.0f + 0.3275911f * ax);
    float poly = t * (0.254829592f + t * (-0.284496736f +
                 t * (1.421413741f + t * (-1.453152027f + t * 1.061405429f))));
    float e  = 1.0f - poly * __expf(-x * x);
    float er = copysignf(e, x);
    return 0.5f * a * (1.0f + er);
}

// ---- workspace layout (bf16 elements) ----
#define WT_OFF   0          // qkv_w^T  [288][96]
#define PJT_OFF  27648      // proj_w^T [96][96]
#define F1T_OFF  36864      // fc1_w^T  [384][96]
#define F2T_OFF  73728      // fc2_w^T  [96][384]
#define WS_ELEMS 110592     // * 2 bytes = 221,184 B

__global__ __launch_bounds__(256) void setup_kernel(
    const float* __restrict__ qkv_w, const float* __restrict__ proj_w,
    const float* __restrict__ fc1_w, const float* __restrict__ fc2_w,
    u16* __restrict__ ws)
{
    int i0 = blockIdx.x * 256 + threadIdx.x;
    int stride = gridDim.x * 256;
    for (int e = i0; e < 27648; e += stride) {          // wT[n][k] = qkv_w[k][n]
        int n = e / 96, k = e - n * 96;
        ws[WT_OFF + e] = f2bf(qkv_w[k * 288 + n]);
    }
    for (int e = i0; e < 9216; e += stride) {           // pjT[n][k]
        int n = e / 96, k = e - n * 96;
        ws[PJT_OFF + e] = f2bf(proj_w[k * 96 + n]);
    }
    for (int e = i0; e < 36864; e += stride) {          // f1T[n][k], n<384
        int n = e / 96, k = e - n * 96;
        ws[F1T_OFF + e] = f2bf(fc1_w[k * 384 + n]);
    }
    for (int e = i0; e < 36864; e += stride) {          // f2T[n][k], n<96, k<384
        int n = e / 384, k = e - n * 384;
        ws[F2T_OFF + e] = f2bf(fc2_w[k * 96 + n]);
    }
}

// =====================================================================
// MFMA attention kernel: one block per window, 7 waves (448 thr)
// x A-fragments hoisted to registers across heads; per-head proj
// accumulation in registers; per-wave LDS chunk staging
// =====================================================================
#define NWV    7
#define QK_LD  40    // Q/K row stride (u16): 80B -> 2-way bank alias (free)
#define VT_LD  232   // V^T row stride
#define STG_LD 40    // per-wave staging row stride

__global__ __launch_bounds__(448) void attn_mfma_kernel(
    const float* __restrict__ x,
    const u16*  __restrict__ ws,
    const float* __restrict__ qkv_b,
    const float* __restrict__ proj_b,
    float* __restrict__ out)
{
    __shared__ __align__(16) u16 Qs[NTP * QK_LD];          // 17,920 B
    __shared__ __align__(16) u16 Ks[NTP * QK_LD];          // 17,920 B
    __shared__ __align__(16) u16 VTs[HD * VT_LD];          // 14,848 B
    __shared__ __align__(16) u16 Stg[NWV * 2 * 16 * STG_LD]; // 17,920 B
    __shared__ int rowsL[NT];

    const int wi  = blockIdx.x;
    const int b   = wi >> 6, ih = (wi >> 3) & 7, iw = wi & 7;
    const int tid = threadIdx.x;
    const int w   = tid >> 6, lane = tid & 63;
    const int l15 = lane & 15, g = lane >> 4;

    // token t=(n,r,col) -> flat row; roll(-3) gather == roll(+3) scatter
    if (tid < NT) {
        int t = tid;
        int n = t / 49, rc = t - n * 49, r = rc / 7, cl = rc - r * 7;
        int hh = ih * 7 + r  + 3; if (hh >= HP) hh -= HP;
        int ww = iw * 7 + cl + 3; if (ww >= WP) ww -= WP;
        rowsL[t] = ((b * NBAND + n) * HP + hh) * WP + ww;
    }
    __syncthreads();

    const u16* wT  = ws + WT_OFF;
    const u16* pjT = ws + PJT_OFF;

    // ---- preload x A-fragments for both owned M-tiles (head-invariant) ----
    short8_t ax[2][3];
    #pragma unroll
    for (int im = 0; im < 2; ++im) {
        int mt = w + NWV * im;
        int t  = mt * 16 + l15;
        bool valid = (t < NT);
        const float* xb = x + (valid ? (size_t)rowsL[t] * C_ : 0);
        #pragma unroll
        for (int ks = 0; ks < 3; ++ks) {
            short8_t a;
            if (valid) {
                const float* p = xb + ks * 32 + g * 8;
                #pragma unroll
                for (int j = 0; j < 8; ++j) a[j] = (s16)f2bf(p[j]);
            } else {
                #pragma unroll
                for (int j = 0; j < 8; ++j) a[j] = 0;
            }
            ax[im][ks] = a;
        }
    }

    f32x4 po[2][6];                       // proj accumulators
    #pragma unroll
    for (int im = 0; im < 2; ++im)
        #pragma unroll
        for (int nj = 0; nj < 6; ++nj)
            po[im][nj] = (f32x4){0.f, 0.f, 0.f, 0.f};

    u16* const st0 = Stg + w * (2 * 16 * STG_LD);

    for (int h = 0; h < NHEADS; ++h) {
        // ---- QKV GEMM for head h ----
        #pragma unroll
        for (int im = 0; im < 2; ++im) {
            int mt = w + NWV * im;
            #pragma unroll
            for (int nj = 0; nj < 6; ++nj) {
                int mat = nj >> 1, nh = nj & 1;
                int ncol = mat * 96 + h * 32 + nh * 16 + l15;
                f32x4 acc = {0.f, 0.f, 0.f, 0.f};
                #pragma unroll
                for (int ks = 0; ks < 3; ++ks) {
                    short8_t bw = *(const short8_t*)(wT + ncol * 96 + ks * 32 + g * 8);
                    acc = __builtin_amdgcn_mfma_f32_16x16x32_bf16(ax[im][ks], bw, acc, 0, 0, 0);
                }
                float bias = qkv_b[ncol];
                int d    = nh * 16 + l15;
                int trow = mt * 16 + 4 * g;
                if (mat == 0) {
                    const float sc = 0.17677669529663687f;      // hd^-0.5 folded into Q
                    #pragma unroll
                    for (int r = 0; r < 4; ++r)
                        Qs[(trow + r) * QK_LD + d] = f2bf((acc[r] + bias) * sc);
                } else if (mat == 1) {
                    #pragma unroll
                    for (int r = 0; r < 4; ++r)
                        Ks[(trow + r) * QK_LD + d] = f2bf(acc[r] + bias);
                } else {                       // V stored transposed, b64 row-writes
                    short4_t v4;
                    #pragma unroll
                    for (int r = 0; r < 4; ++r) v4[r] = (s16)f2bf(acc[r] + bias);
                    *(short4_t*)(VTs + d * VT_LD + trow) = v4;
                }
            }
        }
        __syncthreads();

        // ---- attention + per-head proj accumulate ----
        #pragma unroll
        for (int im = 0; im < 2; ++im) {
            int mt = w + NWV * im;
            short8_t aQ = *(const short8_t*)(Qs + (mt * 16 + l15) * QK_LD + g * 8);
            f32x4 s[13];
            #pragma unroll
            for (int kt = 0; kt < 13; ++kt) {
                short8_t bK = *(const short8_t*)(Ks + (kt * 16 + l15) * QK_LD + g * 8);
                f32x4 z = {0.f, 0.f, 0.f, 0.f};
                s[kt] = __builtin_amdgcn_mfma_f32_16x16x32_bf16(aQ, bK, z, 0, 0, 0);
            }
            if (l15 >= 4) {                   // keys 192+l15 >= 196 invalid
                #pragma unroll
                for (int r = 0; r < 4; ++r) s[12][r] = -1e30f;
            }
            float m[4], sum[4];
            #pragma unroll
            for (int r = 0; r < 4; ++r) {
                float mm = s[0][r];
                #pragma unroll
                for (int kt = 1; kt < 13; ++kt) mm = fmaxf(mm, s[kt][r]);
                #pragma unroll
                for (int o = 1; o < 16; o <<= 1) mm = fmaxf(mm, __shfl_xor(mm, o, 64));
                m[r] = mm;
                sum[r] = 0.f;
            }

            // PV chunked: per kp stage 16x32 of P, read A-frag, 2 MFMA
            f32x4 o0 = {0.f,0.f,0.f,0.f}, o1 = {0.f,0.f,0.f,0.f};
            #pragma unroll
            for (int kp = 0; kp < 7; ++kp) {
                u16* st = st0 + (kp & 1) * (16 * STG_LD);
                #pragma unroll
                for (int r = 0; r < 4; ++r) {
                    float p0 = __expf(s[2 * kp][r] - m[r]);
                    sum[r] += p0;
                    st[(4 * g + r) * STG_LD + l15] = f2bf(p0);
                    if (kp < 6) {
                        float p1 = __expf(s[2 * kp + 1][r] - m[r]);
                        sum[r] += p1;
                        st[(4 * g + r) * STG_LD + 16 + l15] = f2bf(p1);
                    } else {
                        st[(4 * g + r) * STG_LD + 16 + l15] = 0;   // padded keys
                    }
                }
                short8_t aP  = *(const short8_t*)(st + l15 * STG_LD + g * 8);
                short8_t bV0 = *(const short8_t*)(VTs + l15 * VT_LD + kp * 32 + g * 8);
                short8_t bV1 = *(const short8_t*)(VTs + (16 + l15) * VT_LD + kp * 32 + g * 8);
                o0 = __builtin_amdgcn_mfma_f32_16x16x32_bf16(aP, bV0, o0, 0, 0, 0);
                o1 = __builtin_amdgcn_mfma_f32_16x16x32_bf16(aP, bV1, o1, 0, 0, 0);
            }
            #pragma unroll
            for (int r = 0; r < 4; ++r) {
                #pragma unroll
                for (int o = 1; o < 16; o <<= 1) sum[r] += __shfl_xor(sum[r], o, 64);
            }

            // normalize, stage O chunk, accumulate proj k-slice for head h
            {
                u16* st = st0;
                #pragma unroll
                for (int r = 0; r < 4; ++r) {
                    float inv = 1.f / sum[r];
                    st[(4 * g + r) * STG_LD + l15]      = f2bf(o0[r] * inv);
                    st[(4 * g + r) * STG_LD + 16 + l15] = f2bf(o1[r] * inv);
                }
                short8_t aO = *(const short8_t*)(st + l15 * STG_LD + g * 8);
                #pragma unroll
                for (int nj = 0; nj < 6; ++nj) {
                    short8_t bw = *(const short8_t*)(pjT + (nj * 16 + l15) * 96 + h * 32 + g * 8);
                    po[im][nj] = __builtin_amdgcn_mfma_f32_16x16x32_bf16(aO, bw, po[im][nj], 0, 0, 0);
                }
            }
        }
        __syncthreads();
    }

    // ---- epilogue: bias + scatter; row-grouped stores (r outer, nj inner)
    // so each output row's 6x64B chunks issue back-to-back (L2 merge) ----
    #pragma unroll
    for (int im = 0; im < 2; ++im) {
        int mt = w + NWV * im;
        int trow = mt * 16 + 4 * g;
        #pragma unroll
        for (int r = 0; r < 4; ++r) {
            int t = trow + r;
            if (t < NT) {
                float* orow = out + (size_t)rowsL[t] * C_;
                #pragma unroll
                for (int nj = 0; nj < 6; ++nj)
                    orow[nj * 16 + l15] = po[im][nj][r] + proj_b[nj * 16 + l15];
            }
        }
    }
}

// =====================================================================
// MFMA MLP kernel: 64 tokens/block, 4 waves; fc1->gelu->fc2 fused per
// k-chunk through per-wave LDS staging
// =====================================================================
__global__ __launch_bounds__(256) void mlp_mfma_kernel(
    float* __restrict__ io,
    const u16* __restrict__ ws,
    const float* __restrict__ g1, const float* __restrict__ b1,
    const float* __restrict__ g2, const float* __restrict__ b2,
    const float* __restrict__ fc1_b, const float* __restrict__ fc2_b)
{
    __shared__ float xr[64 * 100];                      // 25,600 B (x2' fp32)
    __shared__ __align__(16) u16 yb[64 * 104];          // 13,312 B (LN2, bf16)
    __shared__ __align__(16) u16 stage[4 * 2 * 16 * STG_LD];  // 10,240 B
    __shared__ float mu[64], rs[64], mu2[64], rs2[64];

    const int tid = threadIdx.x;
    const int w = tid >> 6, l15 = (tid & 63) & 15, g = (tid & 63) >> 4;
    float* base = io + (size_t)blockIdx.x * 64 * C_;
    const u16* f1T = ws + F1T_OFF;
    const u16* f2T = ws + F2T_OFF;

    for (int i = tid; i < 64 * 96; i += 256) {
        int t = i / 96, c = i - t * 96;
        xr[t * 100 + c] = base[i];
    }
    __syncthreads();

    // LN1 stats: 4 lanes per token, 24 elems each
    {
        int t = tid >> 2, q = tid & 3;
        const float* row = xr + t * 100 + q * 24;
        float s1 = 0.f, s2 = 0.f;
        #pragma unroll
        for (int j = 0; j < 24; ++j) { float v = row[j]; s1 += v; s2 += v * v; }
        s1 += __shfl_xor(s1, 1); s2 += __shfl_xor(s2, 1);
        s1 += __shfl_xor(s1, 2); s2 += __shfl_xor(s2, 2);
        if (q == 0) {
            float m_ = s1 * (1.f / 96.f);
            mu[t] = m_;
            rs[t] = rsqrtf(s2 * (1.f / 96.f) - m_ * m_ + 1e-5f);
        }
    }
    __syncthreads();
    // x2' = x2 + LN1(x2)
    for (int i = tid; i < 64 * 96; i += 256) {
        int t = i / 96, c = i - t * 96;
        float v = xr[t * 100 + c];
        xr[t * 100 + c] = v + (v - mu[t]) * rs[t] * g1[c] + b1[c];
    }
    __syncthreads();
    // LN2 stats
    {
        int t = tid >> 2, q = tid & 3;
        const float* row = xr + t * 100 + q * 24;
        float s1 = 0.f, s2 = 0.f;
        #pragma unroll
        for (int j = 0; j < 24; ++j) { float v = row[j]; s1 += v; s2 += v * v; }
        s1 += __shfl_xor(s1, 1); s2 += __shfl_xor(s2, 1);
        s1 += __shfl_xor(s1, 2); s2 += __shfl_xor(s2, 2);
        if (q == 0) {
            float m_ = s1 * (1.f / 96.f);
            mu2[t] = m_;
            rs2[t] = rsqrtf(s2 * (1.f / 96.f) - m_ * m_ + 1e-5f);
        }
    }
    __syncthreads();
    for (int i = tid; i < 64 * 96; i += 256) {
        int t = i / 96, c = i - t * 96;
        yb[t * 104 + c] = f2bf((xr[t * 100 + c] - mu2[t]) * rs2[t] * g2[c] + b2[c]);
    }
    __syncthreads();

    // fused fc1 -> gelu -> fc2 (wave w owns M-tile w)
    short8_t aY[3];
    #pragma unroll
    for (int ks = 0; ks < 3; ++ks)
        aY[ks] = *(const short8_t*)(yb + (w * 16 + l15) * 104 + ks * 32 + g * 8);

    f32x4 po[6];
    #pragma unroll
    for (int nj = 0; nj < 6; ++nj) po[nj] = (f32x4){0.f, 0.f, 0.f, 0.f};

    u16* const st0 = stage + w * (2 * 16 * STG_LD);
    for (int ks = 0; ks < 12; ++ks) {         // fc2 k-step = 2 fc1 N-tiles
        u16* st = st0 + (ks & 1) * (16 * STG_LD);
        #pragma unroll
        for (int half = 0; half < 2; ++half) {
            int ncol = (ks * 2 + half) * 16 + l15;
            f32x4 acc = {0.f, 0.f, 0.f, 0.f};
            #pragma unroll
            for (int k2 = 0; k2 < 3; ++k2) {
                short8_t bw = *(const short8_t*)(f1T + ncol * 96 + k2 * 32 + g * 8);
                acc = __builtin_amdgcn_mfma_f32_16x16x32_bf16(aY[k2], bw, acc, 0, 0, 0);
            }
            float bias = fc1_b[ncol];
            #pragma unroll
            for (int r = 0; r < 4; ++r)
                st[(4 * g + r) * STG_LD + half * 16 + l15] = f2bf(gelu_f(acc[r] + bias));
        }
        short8_t aH = *(const short8_t*)(st + l15 * STG_LD + g * 8);
        #pragma unroll
        for (int nj = 0; nj < 6; ++nj) {
            short8_t bw = *(const short8_t*)(f2T + (nj * 16 + l15) * 384 + ks * 32 + g * 8);
            po[nj] = __builtin_amdgcn_mfma_f32_16x16x32_bf16(aH, bw, po[nj], 0, 0, 0);
        }
    }

    // epilogue: residual + bias, row-grouped
    {
        int trow = w * 16 + 4 * g;
        #pragma unroll
        for (int r = 0; r < 4; ++r) {
            int t = trow + r;
            #pragma unroll
            for (int nj = 0; nj < 6; ++nj) {
                int ncol = nj * 16 + l15;
                base[t * 96 + ncol] = xr[t * 100 + ncol] + po[nj][r] + fc2_b[ncol];
            }
        }
    }
}

// =====================================================================
extern "C" void kernel_launch(void* const* d_in, const int* in_sizes, int n_in,
                              void* d_out, int out_size, void* d_ws, size_t ws_size,
                              hipStream_t stream)
{
    (void)in_sizes; (void)n_in; (void)out_size; (void)ws_size;

    const float* x      = (const float*)d_in[0];
    const float* qkv_w  = (const float*)d_in[1];
    const float* qkv_b  = (const float*)d_in[2];
    const float* proj_w = (const float*)d_in[3];
    const float* proj_b = (const float*)d_in[4];
    const float* g1     = (const float*)d_in[5];
    const float* b1     = (const float*)d_in[6];
    const float* g2     = (const float*)d_in[7];
    const float* b2     = (const float*)d_in[8];
    const float* fc1_w  = (const float*)d_in[9];
    const float* fc1_b  = (const float*)d_in[10];
    const float* fc2_w  = (const float*)d_in[11];
    const float* fc2_b  = (const float*)d_in[12];
    float* out = (float*)d_out;
    u16* ws = (u16*)d_ws;

    setup_kernel<<<128, 256, 0, stream>>>(qkv_w, proj_w, fc1_w, fc2_w, ws);
    attn_mfma_kernel<<<BW, 448, 0, stream>>>(x, ws, qkv_b, proj_b, out);
    mlp_mfma_kernel<<<NTOK / 64, 256, 0, stream>>>(out, ws, g1, b1, g2, b2, fc1_b, fc2_b);
}

// Round 8
// 352.666 us; speedup vs baseline: 8.2822x; 1.1011x over previous
//
#include <hip/hip_runtime.h>
#include <hip/hip_bf16.h>

// ---- problem constants ----
#define B_     16
#define NBAND  4
#define HP     56
#define WP     56
#define C_     96
#define NHEADS 3
#define HD     32
#define NT     196                 // tokens per window
#define NTP    224                 // padded to 14x16
#define BW     1024                // windows
#define HID    384
#define NTOK   200704

typedef unsigned short u16;
typedef short s16;
typedef __attribute__((ext_vector_type(8))) s16   short8_t;  // 8 bf16 (4 VGPR)
typedef __attribute__((ext_vector_type(4))) s16   short4_t;
typedef __attribute__((ext_vector_type(4))) float f32x4;

__device__ __forceinline__ float bf2f(u16 u) {
    union { float f; unsigned int i; } x; x.i = ((unsigned int)u) << 16; return x.f;
}
__device__ __forceinline__ u16 f2bf(float f) {
    union { float f; unsigned int i; } x; x.f = f;
    unsigned int r = x.i + 0x7fffu + ((x.i >> 16) & 1u);
    return (u16)(r >> 16);
}
// exact-GELU via A&S 7.1.26 erf approximation (max err 1.5e-7)
__device__ __forceinline__ float gelu_f(float a) {
    float x  = a * 0.70710678118654752f;
    float ax = fabsf(x);
    float t  = 1.0f / (1.0f + 0.3275911f * ax);
    float poly = t * (0.254829592f + t * (-0.284496736f +
                 t * (1.421413741f + t * (-1.453152027f + t * 1.061405429f))));
    float e  = 1.0f - poly * __expf(-x * x);
    float er = copysignf(e, x);
    return 0.5f * a * (1.0f + er);
}

// ---- workspace layout (bf16 elements) ----
#define WT_OFF   0          // qkv_w^T  [288][96]
#define PJT_OFF  27648      // proj_w^T [96][96]
#define F1T_OFF  36864      // fc1_w^T  [384][96]
#define F2T_OFF  73728      // fc2_w^T  [96][384]
#define WS_ELEMS 110592     // * 2 bytes = 221,184 B

__global__ __launch_bounds__(256) void setup_kernel(
    const float* __restrict__ qkv_w, const float* __restrict__ proj_w,
    const float* __restrict__ fc1_w, const float* __restrict__ fc2_w,
    u16* __restrict__ ws)
{
    int i0 = blockIdx.x * 256 + threadIdx.x;
    int stride = gridDim.x * 256;
    for (int e = i0; e < 27648; e += stride) {          // wT[n][k] = qkv_w[k][n]
        int n = e / 96, k = e - n * 96;
        ws[WT_OFF + e] = f2bf(qkv_w[k * 288 + n]);
    }
    for (int e = i0; e < 9216; e += stride) {           // pjT[n][k]
        int n = e / 96, k = e - n * 96;
        ws[PJT_OFF + e] = f2bf(proj_w[k * 96 + n]);
    }
    for (int e = i0; e < 36864; e += stride) {          // f1T[n][k], n<384
        int n = e / 96, k = e - n * 96;
        ws[F1T_OFF + e] = f2bf(fc1_w[k * 384 + n]);
    }
    for (int e = i0; e < 36864; e += stride) {          // f2T[n][k], n<96, k<384
        int n = e / 384, k = e - n * 384;
        ws[F2T_OFF + e] = f2bf(fc2_w[k * 96 + n]);
    }
}

// =====================================================================
// MFMA attention kernel: one block per window, 7 waves (448 thr)
// (byte-identical to the round-5-measured version — passed, ~135 us)
// =====================================================================
#define NWV    7
#define QK_LD  40    // Q/K row stride (u16): 80B -> 2-way bank alias (free)
#define VT_LD  232   // V^T row stride
#define STG_LD 40    // per-wave staging row stride

__global__ __launch_bounds__(448) void attn_mfma_kernel(
    const float* __restrict__ x,
    const u16*  __restrict__ ws,
    const float* __restrict__ qkv_b,
    const float* __restrict__ proj_b,
    float* __restrict__ out)
{
    __shared__ __align__(16) u16 Qs[NTP * QK_LD];          // 17,920 B
    __shared__ __align__(16) u16 Ks[NTP * QK_LD];          // 17,920 B
    __shared__ __align__(16) u16 VTs[HD * VT_LD];          // 14,848 B
    __shared__ __align__(16) u16 Stg[NWV * 2 * 16 * STG_LD]; // 17,920 B
    __shared__ int rowsL[NT];

    const int wi  = blockIdx.x;
    const int b   = wi >> 6, ih = (wi >> 3) & 7, iw = wi & 7;
    const int tid = threadIdx.x;
    const int w   = tid >> 6, lane = tid & 63;
    const int l15 = lane & 15, g = lane >> 4;

    // token t=(n,r,col) -> flat row; roll(-3) gather == roll(+3) scatter
    if (tid < NT) {
        int t = tid;
        int n = t / 49, rc = t - n * 49, r = rc / 7, cl = rc - r * 7;
        int hh = ih * 7 + r  + 3; if (hh >= HP) hh -= HP;
        int ww = iw * 7 + cl + 3; if (ww >= WP) ww -= WP;
        rowsL[t] = ((b * NBAND + n) * HP + hh) * WP + ww;
    }
    __syncthreads();

    const u16* wT  = ws + WT_OFF;
    const u16* pjT = ws + PJT_OFF;

    // ---- preload x A-fragments for both owned M-tiles (head-invariant) ----
    short8_t ax[2][3];
    #pragma unroll
    for (int im = 0; im < 2; ++im) {
        int mt = w + NWV * im;
        int t  = mt * 16 + l15;
        bool valid = (t < NT);
        const float* xb = x + (valid ? (size_t)rowsL[t] * C_ : 0);
        #pragma unroll
        for (int ks = 0; ks < 3; ++ks) {
            short8_t a;
            if (valid) {
                const float* p = xb + ks * 32 + g * 8;
                #pragma unroll
                for (int j = 0; j < 8; ++j) a[j] = (s16)f2bf(p[j]);
            } else {
                #pragma unroll
                for (int j = 0; j < 8; ++j) a[j] = 0;
            }
            ax[im][ks] = a;
        }
    }

    f32x4 po[2][6];                       // proj accumulators
    #pragma unroll
    for (int im = 0; im < 2; ++im)
        #pragma unroll
        for (int nj = 0; nj < 6; ++nj)
            po[im][nj] = (f32x4){0.f, 0.f, 0.f, 0.f};

    u16* const st0 = Stg + w * (2 * 16 * STG_LD);

    for (int h = 0; h < NHEADS; ++h) {
        // ---- QKV GEMM for head h ----
        #pragma unroll
        for (int im = 0; im < 2; ++im) {
            int mt = w + NWV * im;
            #pragma unroll
            for (int nj = 0; nj < 6; ++nj) {
                int mat = nj >> 1, nh = nj & 1;
                int ncol = mat * 96 + h * 32 + nh * 16 + l15;
                f32x4 acc = {0.f, 0.f, 0.f, 0.f};
                #pragma unroll
                for (int ks = 0; ks < 3; ++ks) {
                    short8_t bw = *(const short8_t*)(wT + ncol * 96 + ks * 32 + g * 8);
                    acc = __builtin_amdgcn_mfma_f32_16x16x32_bf16(ax[im][ks], bw, acc, 0, 0, 0);
                }
                float bias = qkv_b[ncol];
                int d    = nh * 16 + l15;
                int trow = mt * 16 + 4 * g;
                if (mat == 0) {
                    const float sc = 0.17677669529663687f;      // hd^-0.5 folded into Q
                    #pragma unroll
                    for (int r = 0; r < 4; ++r)
                        Qs[(trow + r) * QK_LD + d] = f2bf((acc[r] + bias) * sc);
                } else if (mat == 1) {
                    #pragma unroll
                    for (int r = 0; r < 4; ++r)
                        Ks[(trow + r) * QK_LD + d] = f2bf(acc[r] + bias);
                } else {                       // V stored transposed, b64 row-writes
                    short4_t v4;
                    #pragma unroll
                    for (int r = 0; r < 4; ++r) v4[r] = (s16)f2bf(acc[r] + bias);
                    *(short4_t*)(VTs + d * VT_LD + trow) = v4;
                }
            }
        }
        __syncthreads();

        // ---- attention + per-head proj accumulate ----
        #pragma unroll
        for (int im = 0; im < 2; ++im) {
            int mt = w + NWV * im;
            short8_t aQ = *(const short8_t*)(Qs + (mt * 16 + l15) * QK_LD + g * 8);
            f32x4 s[13];
            #pragma unroll
            for (int kt = 0; kt < 13; ++kt) {
                short8_t bK = *(const short8_t*)(Ks + (kt * 16 + l15) * QK_LD + g * 8);
                f32x4 z = {0.f, 0.f, 0.f, 0.f};
                s[kt] = __builtin_amdgcn_mfma_f32_16x16x32_bf16(aQ, bK, z, 0, 0, 0);
            }
            if (l15 >= 4) {                   // keys 192+l15 >= 196 invalid
                #pragma unroll
                for (int r = 0; r < 4; ++r) s[12][r] = -1e30f;
            }
            float m[4], sum[4];
            #pragma unroll
            for (int r = 0; r < 4; ++r) {
                float mm = s[0][r];
                #pragma unroll
                for (int kt = 1; kt < 13; ++kt) mm = fmaxf(mm, s[kt][r]);
                #pragma unroll
                for (int o = 1; o < 16; o <<= 1) mm = fmaxf(mm, __shfl_xor(mm, o, 64));
                m[r] = mm;
                sum[r] = 0.f;
            }

            // PV chunked: per kp stage 16x32 of P, read A-frag, 2 MFMA
            f32x4 o0 = {0.f,0.f,0.f,0.f}, o1 = {0.f,0.f,0.f,0.f};
            #pragma unroll
            for (int kp = 0; kp < 7; ++kp) {
                u16* st = st0 + (kp & 1) * (16 * STG_LD);
                #pragma unroll
                for (int r = 0; r < 4; ++r) {
                    float p0 = __expf(s[2 * kp][r] - m[r]);
                    sum[r] += p0;
                    st[(4 * g + r) * STG_LD + l15] = f2bf(p0);
                    if (kp < 6) {
                        float p1 = __expf(s[2 * kp + 1][r] - m[r]);
                        sum[r] += p1;
                        st[(4 * g + r) * STG_LD + 16 + l15] = f2bf(p1);
                    } else {
                        st[(4 * g + r) * STG_LD + 16 + l15] = 0;   // padded keys
                    }
                }
                short8_t aP  = *(const short8_t*)(st + l15 * STG_LD + g * 8);
                short8_t bV0 = *(const short8_t*)(VTs + l15 * VT_LD + kp * 32 + g * 8);
                short8_t bV1 = *(const short8_t*)(VTs + (16 + l15) * VT_LD + kp * 32 + g * 8);
                o0 = __builtin_amdgcn_mfma_f32_16x16x32_bf16(aP, bV0, o0, 0, 0, 0);
                o1 = __builtin_amdgcn_mfma_f32_16x16x32_bf16(aP, bV1, o1, 0, 0, 0);
            }
            #pragma unroll
            for (int r = 0; r < 4; ++r) {
                #pragma unroll
                for (int o = 1; o < 16; o <<= 1) sum[r] += __shfl_xor(sum[r], o, 64);
            }

            // normalize, stage O chunk, accumulate proj k-slice for head h
            {
                u16* st = st0;
                #pragma unroll
                for (int r = 0; r < 4; ++r) {
                    float inv = 1.f / sum[r];
                    st[(4 * g + r) * STG_LD + l15]      = f2bf(o0[r] * inv);
                    st[(4 * g + r) * STG_LD + 16 + l15] = f2bf(o1[r] * inv);
                }
                short8_t aO = *(const short8_t*)(st + l15 * STG_LD + g * 8);
                #pragma unroll
                for (int nj = 0; nj < 6; ++nj) {
                    short8_t bw = *(const short8_t*)(pjT + (nj * 16 + l15) * 96 + h * 32 + g * 8);
                    po[im][nj] = __builtin_amdgcn_mfma_f32_16x16x32_bf16(aO, bw, po[im][nj], 0, 0, 0);
                }
            }
        }
        __syncthreads();
    }

    // ---- epilogue: bias + scatter; row-grouped stores ----
    #pragma unroll
    for (int im = 0; im < 2; ++im) {
        int mt = w + NWV * im;
        int trow = mt * 16 + 4 * g;
        #pragma unroll
        for (int r = 0; r < 4; ++r) {
            int t = trow + r;
            if (t < NT) {
                float* orow = out + (size_t)rowsL[t] * C_;
                #pragma unroll
                for (int nj = 0; nj < 6; ++nj)
                    orow[nj * 16 + l15] = po[im][nj][r] + proj_b[nj * 16 + l15];
            }
        }
    }
}

// =====================================================================
// MFMA MLP kernel: PROVEN round-4 structure (5-phase LDS LN, yb buffer)
// + software-pipelined B-fragment loads in the fused fc1->gelu->fc2 loop
// (pure scheduling change; numerics identical to the passing version)
// =====================================================================
__global__ __launch_bounds__(256) void mlp_mfma_kernel(
    float* __restrict__ io,
    const u16* __restrict__ ws,
    const float* __restrict__ g1, const float* __restrict__ b1,
    const float* __restrict__ g2, const float* __restrict__ b2,
    const float* __restrict__ fc1_b, const float* __restrict__ fc2_b)
{
    __shared__ float xr[64 * 100];                      // 25,600 B (x2' fp32)
    __shared__ __align__(16) u16 yb[64 * 104];          // 13,312 B (LN2, bf16)
    __shared__ __align__(16) u16 stage[4 * 2 * 16 * STG_LD];  // 10,240 B
    __shared__ float mu[64], rs[64], mu2[64], rs2[64];

    const int tid = threadIdx.x;
    const int w = tid >> 6, l15 = (tid & 63) & 15, g = (tid & 63) >> 4;
    float* base = io + (size_t)blockIdx.x * 64 * C_;
    const u16* f1T = ws + F1T_OFF;
    const u16* f2T = ws + F2T_OFF;

    for (int i = tid; i < 64 * 96; i += 256) {
        int t = i / 96, c = i - t * 96;
        xr[t * 100 + c] = base[i];
    }
    __syncthreads();

    // LN1 stats: 4 lanes per token, 24 elems each
    {
        int t = tid >> 2, q = tid & 3;
        const float* row = xr + t * 100 + q * 24;
        float s1 = 0.f, s2 = 0.f;
        #pragma unroll
        for (int j = 0; j < 24; ++j) { float v = row[j]; s1 += v; s2 += v * v; }
        s1 += __shfl_xor(s1, 1); s2 += __shfl_xor(s2, 1);
        s1 += __shfl_xor(s1, 2); s2 += __shfl_xor(s2, 2);
        if (q == 0) {
            float m_ = s1 * (1.f / 96.f);
            mu[t] = m_;
            rs[t] = rsqrtf(s2 * (1.f / 96.f) - m_ * m_ + 1e-5f);
        }
    }
    __syncthreads();
    // x2' = x2 + LN1(x2)
    for (int i = tid; i < 64 * 96; i += 256) {
        int t = i / 96, c = i - t * 96;
        float v = xr[t * 100 + c];
        xr[t * 100 + c] = v + (v - mu[t]) * rs[t] * g1[c] + b1[c];
    }
    __syncthreads();
    // LN2 stats
    {
        int t = tid >> 2, q = tid & 3;
        const float* row = xr + t * 100 + q * 24;
        float s1 = 0.f, s2 = 0.f;
        #pragma unroll
        for (int j = 0; j < 24; ++j) { float v = row[j]; s1 += v; s2 += v * v; }
        s1 += __shfl_xor(s1, 1); s2 += __shfl_xor(s2, 1);
        s1 += __shfl_xor(s1, 2); s2 += __shfl_xor(s2, 2);
        if (q == 0) {
            float m_ = s1 * (1.f / 96.f);
            mu2[t] = m_;
            rs2[t] = rsqrtf(s2 * (1.f / 96.f) - m_ * m_ + 1e-5f);
        }
    }
    __syncthreads();
    for (int i = tid; i < 64 * 96; i += 256) {
        int t = i / 96, c = i - t * 96;
        yb[t * 104 + c] = f2bf((xr[t * 100 + c] - mu2[t]) * rs2[t] * g2[c] + b2[c]);
    }
    __syncthreads();

    // A-fragments from yb (proven layout)
    short8_t aY[3];
    #pragma unroll
    for (int ks = 0; ks < 3; ++ks)
        aY[ks] = *(const short8_t*)(yb + (w * 16 + l15) * 104 + ks * 32 + g * 8);

    f32x4 po[6];
    #pragma unroll
    for (int nj = 0; nj < 6; ++nj) po[nj] = (f32x4){0.f, 0.f, 0.f, 0.f};

    // ---- B-fragment software pipeline ----
    // c1: fc1 weights for current ks (preloaded); n1: next ks; c2: fc2
    // weights for current ks, issued at top, consumed after fc1+gelu chain.
    short8_t c1[2][3], n1[2][3], c2[6];
    #pragma unroll
    for (int half = 0; half < 2; ++half)
        #pragma unroll
        for (int k2 = 0; k2 < 3; ++k2)
            c1[half][k2] = *(const short8_t*)(f1T + (half * 16 + l15) * 96 + k2 * 32 + g * 8);

    u16* const st0 = stage + w * (2 * 16 * STG_LD);
    for (int ks = 0; ks < 12; ++ks) {          // fc2 k-step = 2 fc1 N-tiles
        u16* st = st0 + (ks & 1) * (16 * STG_LD);

        // issue this-iteration fc2 B loads (latency hidden by fc1+gelu+LDS)
        #pragma unroll
        for (int nj = 0; nj < 6; ++nj)
            c2[nj] = *(const short8_t*)(f2T + (nj * 16 + l15) * 384 + ks * 32 + g * 8);
        // issue next-iteration fc1 B loads (latency hidden by whole iter)
        {
            int ksn = (ks < 11) ? ks + 1 : 11;
            #pragma unroll
            for (int half = 0; half < 2; ++half)
                #pragma unroll
                for (int k2 = 0; k2 < 3; ++k2)
                    n1[half][k2] = *(const short8_t*)(f1T + ((ksn * 2 + half) * 16 + l15) * 96 + k2 * 32 + g * 8);
        }

        // fc1 + gelu with preloaded c1
        #pragma unroll
        for (int half = 0; half < 2; ++half) {
            int ncol = (ks * 2 + half) * 16 + l15;
            f32x4 acc = {0.f, 0.f, 0.f, 0.f};
            #pragma unroll
            for (int k2 = 0; k2 < 3; ++k2)
                acc = __builtin_amdgcn_mfma_f32_16x16x32_bf16(aY[k2], c1[half][k2], acc, 0, 0, 0);
            float bias = fc1_b[ncol];
            #pragma unroll
            for (int r = 0; r < 4; ++r)
                st[(4 * g + r) * STG_LD + half * 16 + l15] = f2bf(gelu_f(acc[r] + bias));
        }
        short8_t aH = *(const short8_t*)(st + l15 * STG_LD + g * 8);
        #pragma unroll
        for (int nj = 0; nj < 6; ++nj)
            po[nj] = __builtin_amdgcn_mfma_f32_16x16x32_bf16(aH, c2[nj], po[nj], 0, 0, 0);

        // rotate pipeline
        #pragma unroll
        for (int half = 0; half < 2; ++half)
            #pragma unroll
            for (int k2 = 0; k2 < 3; ++k2)
                c1[half][k2] = n1[half][k2];
    }

    // epilogue: residual + bias, row-grouped
    {
        int trow = w * 16 + 4 * g;
        #pragma unroll
        for (int r = 0; r < 4; ++r) {
            int t = trow + r;
            #pragma unroll
            for (int nj = 0; nj < 6; ++nj) {
                int ncol = nj * 16 + l15;
                base[t * 96 + ncol] = xr[t * 100 + ncol] + po[nj][r] + fc2_b[ncol];
            }
        }
    }
}

// =====================================================================
extern "C" void kernel_launch(void* const* d_in, const int* in_sizes, int n_in,
                              void* d_out, int out_size, void* d_ws, size_t ws_size,
                              hipStream_t stream)
{
    (void)in_sizes; (void)n_in; (void)out_size; (void)ws_size;

    const float* x      = (const float*)d_in[0];
    const float* qkv_w  = (const float*)d_in[1];
    const float* qkv_b  = (const float*)d_in[2];
    const float* proj_w = (const float*)d_in[3];
    const float* proj_b = (const float*)d_in[4];
    const float* g1     = (const float*)d_in[5];
    const float* b1     = (const float*)d_in[6];
    const float* g2     = (const float*)d_in[7];
    const float* b2     = (const float*)d_in[8];
    const float* fc1_w  = (const float*)d_in[9];
    const float* fc1_b  = (const float*)d_in[10];
    const float* fc2_w  = (const float*)d_in[11];
    const float* fc2_b  = (const float*)d_in[12];
    float* out = (float*)d_out;
    u16* ws = (u16*)d_ws;

    setup_kernel<<<128, 256, 0, stream>>>(qkv_w, proj_w, fc1_w, fc2_w, ws);
    attn_mfma_kernel<<<BW, 448, 0, stream>>>(x, ws, qkv_b, proj_b, out);
    mlp_mfma_kernel<<<NTOK / 64, 256, 0, stream>>>(out, ws, g1, b1, g2, b2, fc1_b, fc2_b);
}